// Round 2
// baseline (4958.866 us; speedup 1.0000x reference)
//
#include <hip/hip_runtime.h>

// NonLocalMeans: rgb (8,3,1024,1024) f32, search 11x11, patch 5x5, circular.
// out(p) = sum_s w(p,s)*rgb(p-s) / sum_s w(p,s),
// w(p,s) = exp(-sqrt(sum_{5x5 patch} (y - y_shifted)^2) * inv_h)

#define HW (1024 * 1024)
#define W 1024
#define MASK 1023

constexpr int TILE = 32;
constexpr int YREG = 46;    // TILE + 2*7 (shift 5 + patch 2)
constexpr int YPITCH = 48;
constexpr int CREG = 42;    // TILE + 2*5
// -log2(e) / (1.0 + 1e-6)
constexpr float NEG_C = -1.4426935981939074f;

// __launch_bounds__(256, 4): 128-VGPR budget. At the default (64 VGPR) the
// compiler spilled the h[5][11] ring to scratch -> 18.5 GB HBM traffic/launch
// (R1 counters: WRITE_SIZE 10.6 GB vs 100 MB output). Working set ~106 VGPRs.
__global__ __launch_bounds__(256, 4)
void nlm_fused(const float* __restrict__ rgb, float* __restrict__ out) {
    __shared__ float  ldsY[YREG * YPITCH];      // 8832 B
    __shared__ float4 ldsC[CREG * CREG];        // 28224 B

    const int tid = threadIdx.x;
    const int batch = blockIdx.z;
    const int by0 = blockIdx.y * TILE;
    const int bx0 = blockIdx.x * TILE;

    const float* base = rgb + (size_t)batch * 3 * HW;

    // ---- stage luminance tile (mean over channels), halo 7 ----
    for (int i = tid; i < YREG * YREG; i += 256) {
        int ry = i / YREG, rx = i - ry * YREG;
        int gy = (by0 + ry - 7) & MASK;
        int gx = (bx0 + rx - 7) & MASK;
        int off = gy * W + gx;
        float v = (base[off] + base[off + HW] + base[off + 2 * HW]) * (1.0f / 3.0f);
        ldsY[ry * YPITCH + rx] = v;
    }
    // ---- stage rgb tile as float4, halo 5 ----
    for (int i = tid; i < CREG * CREG; i += 256) {
        int ry = i / CREG, rx = i - ry * CREG;
        int gy = (by0 + ry - 5) & MASK;
        int gx = (bx0 + rx - 5) & MASK;
        int off = gy * W + gx;
        ldsC[i] = make_float4(base[off], base[off + HW], base[off + 2 * HW], 0.0f);
    }
    __syncthreads();

    const int tx = tid & 31;          // output column within tile
    const int y0 = (tid >> 5) * 4;    // 4-pixel column run per thread

    float accR[4] = {0.f, 0.f, 0.f, 0.f};
    float accG[4] = {0.f, 0.f, 0.f, 0.f};
    float accB[4] = {0.f, 0.f, 0.f, 0.f};
    float accW[4] = {0.f, 0.f, 0.f, 0.f};

    for (int dy = -5; dy <= 5; ++dy) {
        float h[5][11];   // ring of horizontal 5-sums, rows rr-4..rr
        #pragma unroll
        for (int rr = 0; rr < 8; ++rr) {
            const int r  = y0 - 2 + rr;   // tile-local row, [-2, 33]
            const int rs = r - dy;        // shifted row, [-7, 38]
            const float* ycp = &ldsY[(r + 7) * YPITCH + tx + 5];
            const float* ywp = &ldsY[(rs + 7) * YPITCH + tx];
            const float c0 = ycp[0], c1 = ycp[1], c2 = ycp[2], c3 = ycp[3], c4 = ycp[4];
            float wv[15];
            #pragma unroll
            for (int j = 0; j < 15; ++j) wv[j] = ywp[j];
            // horizontal 5-sums for all 11 dx via sliding window
            #pragma unroll
            for (int dxi = 0; dxi < 11; ++dxi) {
                // window index j = b + 10 - dxi  (dx = dxi - 5)
                float d0 = c0 - wv[10 - dxi];
                float d1 = c1 - wv[11 - dxi];
                float d2 = c2 - wv[12 - dxi];
                float d3 = c3 - wv[13 - dxi];
                float d4 = c4 - wv[14 - dxi];
                float s = d0 * d0;
                s = fmaf(d1, d1, s);
                s = fmaf(d2, d2, s);
                s = fmaf(d3, d3, s);
                s = fmaf(d4, d4, s);
                h[rr % 5][dxi] = s;
            }
            if (rr >= 4) {
                const int yo = rr - 4;    // output row 0..3
                const float4* crow = &ldsC[(y0 + yo - dy + 5) * CREG + tx + 10];
                #pragma unroll
                for (int dxi = 0; dxi < 11; ++dxi) {
                    // all 5 ring slots hold rows yo-2..yo+2 for this dy
                    float v = h[0][dxi] + h[1][dxi] + h[2][dxi] + h[3][dxi] + h[4][dxi];
                    float dist = __builtin_amdgcn_sqrtf(v);
                    float w = __builtin_amdgcn_exp2f(dist * NEG_C);
                    float4 px = crow[-dxi];
                    accR[yo] = fmaf(w, px.x, accR[yo]);
                    accG[yo] = fmaf(w, px.y, accG[yo]);
                    accB[yo] = fmaf(w, px.z, accB[yo]);
                    accW[yo] += w;
                }
            }
        }
    }

    float* obase = out + (size_t)batch * 3 * HW;
    #pragma unroll
    for (int yo = 0; yo < 4; ++yo) {
        const int gy = by0 + y0 + yo;
        const int gx = bx0 + tx;
        const int off = gy * W + gx;
        const float inv = 1.0f / accW[yo];
        obase[off]          = accR[yo] * inv;
        obase[off + HW]     = accG[yo] * inv;
        obase[off + 2 * HW] = accB[yo] * inv;
    }
}

extern "C" void kernel_launch(void* const* d_in, const int* in_sizes, int n_in,
                              void* d_out, int out_size, void* d_ws, size_t ws_size,
                              hipStream_t stream) {
    const float* rgb = (const float*)d_in[0];
    float* out = (float*)d_out;
    dim3 grid(W / TILE, W / TILE, 8);
    dim3 block(256, 1, 1);
    hipLaunchKernelGGL(nlm_fused, grid, block, 0, stream, rgb, out);
}

// Round 3
// 1447.547 us; speedup vs baseline: 3.4257x; 3.4257x over previous
//
#include <hip/hip_runtime.h>

// NonLocalMeans: rgb (8,3,1024,1024) f32, search 11x11, patch 5x5, circular.
// out(p) = sum_s w(p,s)*rgb(p-s) / sum_s w(p,s),
// w(p,s) = exp(-sqrt(box5x5((y - y_shift)^2)) * inv_h)
//
// R1/R2 lesson: local arrays (h[5][11], wv[15]) were NOT promoted to VGPRs
// (VGPR_Count stuck at 64, 11-19 GB of scratch HBM traffic). This version has
// ZERO local arrays: the 5-row ring is five R11 structs rotated by macro
// argument permutation; all loops over ring/window indices are macro-unrolled
// with literal indices. Nothing can be an alloca.

#define HW (1024 * 1024)
#define W 1024
#define MASK 1023

constexpr int TILE = 32;
constexpr int YREG = 46;    // TILE + 2*7 (shift 5 + patch 2)
constexpr int YPITCH = 48;
constexpr int CREG = 42;    // TILE + 2*5
// -log2(e) / (1.0 + 1e-6)
constexpr float NEG_C = -1.4426935981939074f;

struct R11 { float a0,a1,a2,a3,a4,a5,a6,a7,a8,a9,a10; };

// squared-diff 5-tap horizontal sum; c0..c4 are in scope at expansion site
#define SQ5(W0,W1,W2,W3,W4) \
    fmaf(c4-(W4), c4-(W4), fmaf(c3-(W3), c3-(W3), fmaf(c2-(W2), c2-(W2), \
    fmaf(c1-(W1), c1-(W1), (c0-(W0))*(c0-(W0))))))

// row r = y0-2+RR (LDS row index y0+5+RR); shifted row r-dy.
// DST.aJ = horizontal 5-sum of squared diffs for dx = J-5.
#define ROW(RR, DST) do {                                                   \
    const float* ycp = &ldsY[(y0 + 5 + (RR)) * YPITCH + tx + 5];            \
    const float* ywp = &ldsY[(y0 + 5 + (RR) - dy) * YPITCH + tx];           \
    const float c0=ycp[0],c1=ycp[1],c2=ycp[2],c3=ycp[3],c4=ycp[4];          \
    const float w0 =ywp[0], w1 =ywp[1], w2 =ywp[2], w3 =ywp[3], w4 =ywp[4]; \
    const float w5 =ywp[5], w6 =ywp[6], w7 =ywp[7], w8 =ywp[8], w9 =ywp[9]; \
    const float w10=ywp[10],w11=ywp[11],w12=ywp[12],w13=ywp[13],w14=ywp[14];\
    DST.a0  = SQ5(w10,w11,w12,w13,w14);                                     \
    DST.a1  = SQ5(w9, w10,w11,w12,w13);                                     \
    DST.a2  = SQ5(w8, w9, w10,w11,w12);                                     \
    DST.a3  = SQ5(w7, w8, w9, w10,w11);                                     \
    DST.a4  = SQ5(w6, w7, w8, w9, w10);                                     \
    DST.a5  = SQ5(w5, w6, w7, w8, w9);                                      \
    DST.a6  = SQ5(w4, w5, w6, w7, w8);                                      \
    DST.a7  = SQ5(w3, w4, w5, w6, w7);                                      \
    DST.a8  = SQ5(w2, w3, w4, w5, w6);                                      \
    DST.a9  = SQ5(w1, w2, w3, w4, w5);                                      \
    DST.a10 = SQ5(w0, w1, w2, w3, w4);                                      \
} while (0)

#define ACC1(YO, J, P,Q,Rr,S,T) do {                                        \
    float v = P.a##J + Q.a##J + Rr.a##J + S.a##J + T.a##J;                  \
    float dist = __builtin_amdgcn_sqrtf(v);                                 \
    float wgt = __builtin_amdgcn_exp2f(dist * NEG_C);                       \
    float4 px = crow[-(J)];                                                 \
    aR##YO = fmaf(wgt, px.x, aR##YO);                                       \
    aG##YO = fmaf(wgt, px.y, aG##YO);                                       \
    aB##YO = fmaf(wgt, px.z, aB##YO);                                       \
    aW##YO += wgt;                                                          \
} while (0)

// ring slots P..T hold patch rows yo-2..yo+2 for this dy
#define ACCUM(YO, P,Q,Rr,S,T) do {                                          \
    const float4* crow = &ldsC[(y0 + (YO) - dy + 5) * CREG + tx + 10];      \
    ACC1(YO,0 ,P,Q,Rr,S,T); ACC1(YO,1 ,P,Q,Rr,S,T);                         \
    ACC1(YO,2 ,P,Q,Rr,S,T); ACC1(YO,3 ,P,Q,Rr,S,T);                         \
    ACC1(YO,4 ,P,Q,Rr,S,T); ACC1(YO,5 ,P,Q,Rr,S,T);                         \
    ACC1(YO,6 ,P,Q,Rr,S,T); ACC1(YO,7 ,P,Q,Rr,S,T);                         \
    ACC1(YO,8 ,P,Q,Rr,S,T); ACC1(YO,9 ,P,Q,Rr,S,T);                         \
    ACC1(YO,10,P,Q,Rr,S,T);                                                 \
} while (0)

#define STORE(YO) do {                                                      \
    const int off = (by0 + y0 + (YO)) * W + bx0 + tx;                       \
    const float inv = 1.0f / aW##YO;                                        \
    obase[off]          = aR##YO * inv;                                     \
    obase[off + HW]     = aG##YO * inv;                                     \
    obase[off + 2 * HW] = aB##YO * inv;                                     \
} while (0)

__global__ __launch_bounds__(256, 4)
void nlm_fused(const float* __restrict__ rgb, float* __restrict__ out) {
    __shared__ float  ldsY[YREG * YPITCH];      // 8832 B
    __shared__ float4 ldsC[CREG * CREG];        // 28224 B

    const int tid = threadIdx.x;
    const int batch = blockIdx.z;
    const int by0 = blockIdx.y * TILE;
    const int bx0 = blockIdx.x * TILE;

    const float* base = rgb + (size_t)batch * 3 * HW;

    // ---- stage luminance tile (mean over channels), halo 7 ----
    for (int i = tid; i < YREG * YREG; i += 256) {
        int ry = i / YREG, rx = i - ry * YREG;
        int gy = (by0 + ry - 7) & MASK;
        int gx = (bx0 + rx - 7) & MASK;
        int off = gy * W + gx;
        float v = (base[off] + base[off + HW] + base[off + 2 * HW]) * (1.0f / 3.0f);
        ldsY[ry * YPITCH + rx] = v;
    }
    // ---- stage rgb tile as float4, halo 5 ----
    for (int i = tid; i < CREG * CREG; i += 256) {
        int ry = i / CREG, rx = i - ry * CREG;
        int gy = (by0 + ry - 5) & MASK;
        int gx = (bx0 + rx - 5) & MASK;
        int off = gy * W + gx;
        ldsC[i] = make_float4(base[off], base[off + HW], base[off + 2 * HW], 0.0f);
    }
    __syncthreads();

    const int tx = tid & 31;          // output column within tile
    const int y0 = (tid >> 5) * 4;    // 4-pixel column run per thread

    float aR0=0.f, aG0=0.f, aB0=0.f, aW0=0.f;
    float aR1=0.f, aG1=0.f, aB1=0.f, aW1=0.f;
    float aR2=0.f, aG2=0.f, aB2=0.f, aW2=0.f;
    float aR3=0.f, aG3=0.f, aB3=0.f, aW3=0.f;

    #pragma clang loop unroll(disable)
    for (int dy = -5; dy <= 5; ++dy) {
        R11 s0, s1, s2, s3, s4;
        ROW(0, s0);
        ROW(1, s1);
        ROW(2, s2);
        ROW(3, s3);
        ROW(4, s4); ACCUM(0, s0, s1, s2, s3, s4);
        ROW(5, s0); ACCUM(1, s1, s2, s3, s4, s0);
        ROW(6, s1); ACCUM(2, s2, s3, s4, s0, s1);
        ROW(7, s2); ACCUM(3, s3, s4, s0, s1, s2);
    }

    float* obase = out + (size_t)batch * 3 * HW;
    STORE(0);
    STORE(1);
    STORE(2);
    STORE(3);
}

extern "C" void kernel_launch(void* const* d_in, const int* in_sizes, int n_in,
                              void* d_out, int out_size, void* d_ws, size_t ws_size,
                              hipStream_t stream) {
    const float* rgb = (const float*)d_in[0];
    float* out = (float*)d_out;
    dim3 grid(W / TILE, W / TILE, 8);
    dim3 block(256, 1, 1);
    hipLaunchKernelGGL(nlm_fused, grid, block, 0, stream, rgb, out);
}